// Round 18
// baseline (388.738 us; speedup 1.0000x reference)
//
#include <hip/hip_runtime.h>
#include <hip/hip_bf16.h>
#include <math.h>

#define N_NODES 50000
#define N_EDGES 600000
#define N_GRAPHS 512
#define DIM 128
#define OUTD 64
#define EPSV 1e-6f
#define BSTRIDE 64     // bucket slots per node; mean deg 12, P(deg>64) ~ 0
#define EBLK4 586      // ceil(150000 quads / 256)
#define PREP_BLK 64    // 16384 threads = DIM*DIM
#define NGRP 12500     // node groups of 4 (one per wave)

typedef __attribute__((ext_vector_type(8))) short bf16x8;
typedef __attribute__((ext_vector_type(4))) float f32x4;
typedef __attribute__((ext_vector_type(4))) unsigned u32x4;

__device__ __forceinline__ float sgn(float v) {
    return (v > 0.f) ? 1.f : ((v < 0.f) ? -1.f : 0.f);
}

__device__ __forceinline__ float cube_signed(float v) {
    float m = fabsf(v) + EPSV;
    return sgn(v) * m * m * m;
}

__device__ __forceinline__ float cbrt_pos(float m) {
    return exp2f(log2f(m) * (1.0f / 3.0f));
}

__device__ __forceinline__ unsigned short f2bf(float f) {
    unsigned u = __float_as_uint(f);
    unsigned r = (u + 0x7fff + ((u >> 16) & 1)) >> 16;   // RNE
    return (unsigned short)r;
}

__device__ __forceinline__ float bf2f(unsigned short h) {
    return __uint_as_float(((unsigned)h) << 16);
}

// ---- buildprep: 4-edge/thread bucket fill || W split + gstart + T zero -----
// deg must be zeroed (memsetAsync) before this kernel.

__global__ void buildprep(const int* __restrict__ src, const int* __restrict__ dst,
                          int* __restrict__ deg, unsigned short* __restrict__ csr,
                          const float* __restrict__ W1, const float* __restrict__ W2,
                          unsigned short* __restrict__ W1hi, unsigned short* __restrict__ W1lo,
                          unsigned short* __restrict__ W2hi, unsigned short* __restrict__ W2lo,
                          const int* __restrict__ batch, int* __restrict__ gstart,
                          unsigned* __restrict__ T1z, unsigned* __restrict__ T2z) {
    int b = blockIdx.x;
    if (b < EBLK4) {
        int e4 = b * 256 + threadIdx.x;
        if (e4 < N_EDGES / 4) {
            uint4 s4 = ((const uint4*)src)[e4];
            uint4 d4 = ((const uint4*)dst)[e4];
            int d0 = (int)d4.x, d1 = (int)d4.y, d2 = (int)d4.z, d3 = (int)d4.w;
            int sl0 = atomicAdd(&deg[d0], 1);
            int sl1 = atomicAdd(&deg[d1], 1);
            int sl2 = atomicAdd(&deg[d2], 1);
            int sl3 = atomicAdd(&deg[d3], 1);
            if (sl0 < BSTRIDE) csr[d0 * BSTRIDE + sl0] = (unsigned short)(s4.x + 1);
            if (sl1 < BSTRIDE) csr[d1 * BSTRIDE + sl1] = (unsigned short)(s4.y + 1);
            if (sl2 < BSTRIDE) csr[d2 * BSTRIDE + sl2] = (unsigned short)(s4.z + 1);
            if (sl3 < BSTRIDE) csr[d3 * BSTRIDE + sl3] = (unsigned short)(s4.w + 1);
        }
        return;
    }
    int i = (b - EBLK4) * 256 + threadIdx.x;
    {
        float w = W1[i];
        unsigned short h = f2bf(w);
        W1hi[i] = h;
        W1lo[i] = f2bf(w - bf2f(h));
        w = W2[i];
        h = f2bf(w);
        W2hi[i] = h;
        W2lo[i] = f2bf(w - bf2f(h));
    }
    if (i < 64) { T1z[i] = 0u; T2z[i] = 0u; }   // dummy zero row 0
    if (i <= N_GRAPHS) {
        int lo = 0, hi = N_NODES;
        while (lo < hi) {
            int mid = (lo + hi) >> 1;
            if (batch[mid] < i) lo = mid + 1; else hi = mid;
        }
        gstart[i] = lo;
    }
}

// ---- Linear+cube via split-bf16 MFMA: T[n+1] = cube(X @ W^T + B), bf16 -----
// R16-proven: wave owns 16-node tile, LDS-staged coalesced stores.

__global__ __launch_bounds__(256) void linear_cube_mfma(const float* __restrict__ X,
                                                        const unsigned short* __restrict__ Whi,
                                                        const unsigned short* __restrict__ Wlo,
                                                        const float* __restrict__ B,
                                                        unsigned short* __restrict__ T) {
    __shared__ unsigned short Tl[4][16][DIM];
    int wave = threadIdx.x >> 6;
    int lane = threadIdx.x & 63;
    int tile = blockIdx.x * 4 + wave;
    if (tile >= N_NODES / 16) return;
    int n0 = tile * 16;
    int r = lane & 15;    // A-row (node) on load side; B/D column (output)
    int g = lane >> 4;    // k-group

    bf16x8 xh[4], xl[4];
    const float* xrow = X + (size_t)(n0 + r) * DIM + g * 8;
    #pragma unroll
    for (int kb = 0; kb < 4; kb++) {
        float4 a = *(const float4*)(xrow + kb * 32);
        float4 b = *(const float4*)(xrow + kb * 32 + 4);
        float v[8] = {a.x, a.y, a.z, a.w, b.x, b.y, b.z, b.w};
        #pragma unroll
        for (int j = 0; j < 8; j++) {
            unsigned short h = f2bf(v[j]);
            float rem = v[j] - bf2f(h);
            xh[kb][j] = (short)h;
            xl[kb][j] = (short)f2bf(rem);
        }
    }

    #pragma unroll
    for (int ct = 0; ct < 8; ct++) {
        const unsigned short* whbase = Whi + (size_t)(ct * 16 + r) * DIM + g * 8;
        const unsigned short* wlbase = Wlo + (size_t)(ct * 16 + r) * DIM + g * 8;
        f32x4 acc = {0.f, 0.f, 0.f, 0.f};
        #pragma unroll
        for (int kb = 0; kb < 4; kb++) {
            bf16x8 wh = *(const bf16x8*)(whbase + kb * 32);
            bf16x8 wl = *(const bf16x8*)(wlbase + kb * 32);
            acc = __builtin_amdgcn_mfma_f32_16x16x32_bf16(xh[kb], wh, acc, 0, 0, 0);
            acc = __builtin_amdgcn_mfma_f32_16x16x32_bf16(xl[kb], wh, acc, 0, 0, 0);
            acc = __builtin_amdgcn_mfma_f32_16x16x32_bf16(xh[kb], wl, acc, 0, 0, 0);
        }
        float bias = B[ct * 16 + r];
        #pragma unroll
        for (int q = 0; q < 4; q++) {
            int node = g * 4 + q;   // D row = (lane>>4)*4 + reg  [m89]
            float h = acc[q] + bias;
            Tl[wave][node][ct * 16 + r] = f2bf(cube_signed(h));
        }
    }

    uint4* dstg = (uint4*)(T + (size_t)(n0 + 1) * DIM);
    const uint4* srcl = (const uint4*)&Tl[wave][0][0];
    #pragma unroll
    for (int i = 0; i < 4; i++) {
        dstg[i * 64 + lane] = srcl[i * 64 + lane];
    }
}

// ---- Sliced gather: pass-major, 64B/row slice fits per-XCD L2 --------------
// grid = 4 passes x NGRP blocks (pass-major dispatch order -> resident cohort
// walks one 3.2MB slice at a time). Block = 4 waves x 1 node. Lane layout:
// edge slot es = lane>>2, feature quad q = lane&3; one uint4 load covers 16
// edges x 64B per chunk. mode 0: cbrt+relu -> bf16 hi/lo planes (layer 1).
// mode 1: cbrt -> fp32 P (layer 2). Bucket loads and outputs non-temporal.

__global__ __launch_bounds__(256) void agg_sliced(const unsigned* __restrict__ T32,
                                                  const int* __restrict__ deg,
                                                  const unsigned short* __restrict__ csr,
                                                  unsigned* __restrict__ Phi,
                                                  unsigned* __restrict__ Plo,
                                                  float* __restrict__ P, int mode) {
    int bid = blockIdx.x;
    int pass = bid / NGRP;
    int grp = bid - pass * NGRP;
    int wave = threadIdx.x >> 6;
    int lane = threadIdx.x & 63;
    int nd = grp * 4 + wave;
    int es = lane >> 2, q = lane & 3;

    int d = deg[nd];
    int cnt = d < BSTRIDE ? d : BSTRIDE;
    const unsigned short* bucket = csr + (size_t)nd * BSTRIDE;
    int myidx = (lane < cnt) ? (int)__builtin_nontemporal_load(&bucket[lane]) : 0;

    float a[8];
    #pragma unroll
    for (int j = 0; j < 8; j++) a[j] = 0.f;

    for (int i = 0; i < cnt; i += 16) {
        int s = __shfl(myidx, i + es, 64);
        u32x4 u = *(const u32x4*)(T32 + (size_t)s * 64 + pass * 16 + q * 4);
        a[0] += __uint_as_float(u.x << 16);
        a[1] += __uint_as_float(u.x & 0xffff0000u);
        a[2] += __uint_as_float(u.y << 16);
        a[3] += __uint_as_float(u.y & 0xffff0000u);
        a[4] += __uint_as_float(u.z << 16);
        a[5] += __uint_as_float(u.z & 0xffff0000u);
        a[6] += __uint_as_float(u.w << 16);
        a[7] += __uint_as_float(u.w & 0xffff0000u);
    }
    #pragma unroll
    for (int j = 0; j < 8; j++) {
        a[j] += __shfl_xor(a[j], 4, 64);
        a[j] += __shfl_xor(a[j], 8, 64);
        a[j] += __shfl_xor(a[j], 16, 64);
        a[j] += __shfl_xor(a[j], 32, 64);
    }

    if (es == 0) {
        float c = (float)(d > 1 ? d : 1);
        float r[8];
        #pragma unroll
        for (int j = 0; j < 8; j++) {
            float m = a[j] / c;
            float v = sgn(m) * cbrt_pos(fabsf(m) + EPSV);
            r[j] = (mode == 0) ? fmaxf(v, 0.f) : v;
        }
        if (mode == 0) {
            u32x4 hw, lw;
            unsigned short h0, h1;
            h0 = f2bf(r[0]); h1 = f2bf(r[1]);
            hw.x = (unsigned)h0 | ((unsigned)h1 << 16);
            lw.x = (unsigned)f2bf(r[0] - bf2f(h0)) | ((unsigned)f2bf(r[1] - bf2f(h1)) << 16);
            h0 = f2bf(r[2]); h1 = f2bf(r[3]);
            hw.y = (unsigned)h0 | ((unsigned)h1 << 16);
            lw.y = (unsigned)f2bf(r[2] - bf2f(h0)) | ((unsigned)f2bf(r[3] - bf2f(h1)) << 16);
            h0 = f2bf(r[4]); h1 = f2bf(r[5]);
            hw.z = (unsigned)h0 | ((unsigned)h1 << 16);
            lw.z = (unsigned)f2bf(r[4] - bf2f(h0)) | ((unsigned)f2bf(r[5] - bf2f(h1)) << 16);
            h0 = f2bf(r[6]); h1 = f2bf(r[7]);
            hw.w = (unsigned)h0 | ((unsigned)h1 << 16);
            lw.w = (unsigned)f2bf(r[6] - bf2f(h0)) | ((unsigned)f2bf(r[7] - bf2f(h1)) << 16);
            __builtin_nontemporal_store(hw, (u32x4*)(Phi + (size_t)nd * 64 + pass * 16 + q * 4));
            __builtin_nontemporal_store(lw, (u32x4*)(Plo + (size_t)nd * 64 + pass * 16 + q * 4));
        } else {
            f32x4 w0 = {r[0], r[1], r[2], r[3]};
            f32x4 w1 = {r[4], r[5], r[6], r[7]};
            float* dst = P + (size_t)nd * DIM + pass * 32 + q * 8;
            __builtin_nontemporal_store(w0, (f32x4*)dst);
            __builtin_nontemporal_store(w1, (f32x4*)(dst + 4));
        }
    }
}

// ---- lin2: planes -> MFMA -> T2 (no split VALU; fragments load direct) -----

__global__ __launch_bounds__(256) void lin2_mfma(const unsigned* __restrict__ Phi,
                                                 const unsigned* __restrict__ Plo,
                                                 const unsigned short* __restrict__ Whi,
                                                 const unsigned short* __restrict__ Wlo,
                                                 const float* __restrict__ B,
                                                 unsigned short* __restrict__ T) {
    __shared__ unsigned short Tl[4][16][DIM];
    int wave = threadIdx.x >> 6;
    int lane = threadIdx.x & 63;
    int tile = blockIdx.x * 4 + wave;
    if (tile >= N_NODES / 16) return;
    int n0 = tile * 16;
    int r = lane & 15;
    int g = lane >> 4;

    bf16x8 xh[4], xl[4];
    #pragma unroll
    for (int kb = 0; kb < 4; kb++) {
        xh[kb] = *(const bf16x8*)(Phi + (size_t)(n0 + r) * 64 + kb * 16 + g * 4);
        xl[kb] = *(const bf16x8*)(Plo + (size_t)(n0 + r) * 64 + kb * 16 + g * 4);
    }

    #pragma unroll
    for (int ct = 0; ct < 8; ct++) {
        const unsigned short* whbase = Whi + (size_t)(ct * 16 + r) * DIM + g * 8;
        const unsigned short* wlbase = Wlo + (size_t)(ct * 16 + r) * DIM + g * 8;
        f32x4 acc = {0.f, 0.f, 0.f, 0.f};
        #pragma unroll
        for (int kb = 0; kb < 4; kb++) {
            bf16x8 wh = *(const bf16x8*)(whbase + kb * 32);
            bf16x8 wl = *(const bf16x8*)(wlbase + kb * 32);
            acc = __builtin_amdgcn_mfma_f32_16x16x32_bf16(xh[kb], wh, acc, 0, 0, 0);
            acc = __builtin_amdgcn_mfma_f32_16x16x32_bf16(xl[kb], wh, acc, 0, 0, 0);
            acc = __builtin_amdgcn_mfma_f32_16x16x32_bf16(xh[kb], wl, acc, 0, 0, 0);
        }
        float bias = B[ct * 16 + r];
        #pragma unroll
        for (int q = 0; q < 4; q++) {
            int node = g * 4 + q;
            float h = acc[q] + bias;
            Tl[wave][node][ct * 16 + r] = f2bf(cube_signed(h));
        }
    }

    uint4* dstg = (uint4*)(T + (size_t)(n0 + 1) * DIM);
    const uint4* srcl = (const uint4*)&Tl[wave][0][0];
    #pragma unroll
    for (int i = 0; i < 4; i++) {
        dstg[i * 64 + lane] = srcl[i * 64 + lane];
    }
}

// ---- Fused graph pool + final linear ---------------------------------------

__global__ __launch_bounds__(128) void pool_final(const float* __restrict__ P,
                                                  const int* __restrict__ gstart,
                                                  const float* __restrict__ Wout,
                                                  const float* __restrict__ bout,
                                                  float* __restrict__ out) {
    __shared__ float R[DIM];
    __shared__ float partial[128];
    int g = blockIdx.x, f = threadIdx.x;
    int s = gstart[g], e = gstart[g + 1];
    float acc = 0.f;
    for (int i = s; i < e; i++) {
        float v = P[(size_t)i * DIM + f];
        float m = fabsf(v) + EPSV;
        acc += sgn(v) * m * m;
    }
    int cnt = e - s;
    float c = (float)(cnt > 1 ? cnt : 1);
    float mean = acc / c;
    R[f] = sgn(mean) * sqrtf(fabsf(mean) + EPSV);
    __syncthreads();

    int o = f & 63;
    int half = f >> 6;
    const float4* W4 = (const float4*)Wout + o * 32 + half * 16;
    const float4* R4 = (const float4*)R + half * 16;
    float a = 0.f;
    #pragma unroll
    for (int k = 0; k < 16; k++) {
        float4 w = W4[k];
        float4 r = R4[k];
        a += r.x * w.x + r.y * w.y + r.z * w.z + r.w * w.w;
    }
    partial[f] = a;
    __syncthreads();
    if (f < OUTD) out[(size_t)g * OUTD + f] = bout[f] + partial[f] + partial[f + 64];
}

// ---- launch ----------------------------------------------------------------

extern "C" void kernel_launch(void* const* d_in, const int* in_sizes, int n_in,
                              void* d_out, int out_size, void* d_ws, size_t ws_size,
                              hipStream_t stream) {
    const float* x    = (const float*)d_in[0];
    const float* W1   = (const float*)d_in[1];
    const float* b1   = (const float*)d_in[2];
    const float* W2   = (const float*)d_in[3];
    const float* b2   = (const float*)d_in[4];
    const float* Wout = (const float*)d_in[5];
    const float* bout = (const float*)d_in[6];
    const int* edge   = (const int*)d_in[7];
    const int* batch  = (const int*)d_in[8];
    const int* srcp = edge;
    const int* dstp = edge + N_EDGES;
    float* out = (float*)d_out;

    char* ws = (char*)d_ws;
    size_t off = 0;
    auto alloc = [&](size_t bytes) -> char* {
        char* p = ws + off;
        off += (bytes + 255) / 256 * 256;
        return p;
    };
    unsigned short* T1 = (unsigned short*)alloc((size_t)(N_NODES + 1) * DIM * 2);
    unsigned short* T2 = (unsigned short*)alloc((size_t)(N_NODES + 1) * DIM * 2);
    float* P        = (float*)alloc((size_t)N_NODES * DIM * 4);
    unsigned* Phi   = (unsigned*)alloc((size_t)N_NODES * 64 * 4);
    unsigned* Plo   = (unsigned*)alloc((size_t)N_NODES * 64 * 4);
    int*   deg      = (int*)alloc((size_t)N_NODES * 4);
    unsigned short* csr = (unsigned short*)alloc((size_t)N_NODES * BSTRIDE * 2);
    int*   gstart   = (int*)alloc((size_t)(N_GRAPHS + 1) * 4);
    unsigned short* W1hi = (unsigned short*)alloc((size_t)DIM * DIM * 2);
    unsigned short* W1lo = (unsigned short*)alloc((size_t)DIM * DIM * 2);
    unsigned short* W2hi = (unsigned short*)alloc((size_t)DIM * DIM * 2);
    unsigned short* W2lo = (unsigned short*)alloc((size_t)DIM * DIM * 2);

    hipMemsetAsync(deg, 0, (size_t)N_NODES * 4, stream);
    buildprep<<<EBLK4 + PREP_BLK, 256, 0, stream>>>(srcp, dstp, deg, csr,
                                                    W1, W2, W1hi, W1lo, W2hi, W2lo,
                                                    batch, gstart,
                                                    (unsigned*)T1, (unsigned*)T2);

    const int TILES = N_NODES / 16;           // 3125
    const int LBLK = (TILES + 3) / 4;         // 782 blocks x 4 waves
    linear_cube_mfma<<<LBLK, 256, 0, stream>>>(x, W1hi, W1lo, b1, T1);
    agg_sliced<<<4 * NGRP, 256, 0, stream>>>((const unsigned*)T1, deg, csr,
                                             Phi, Plo, P, 0);
    lin2_mfma<<<LBLK, 256, 0, stream>>>(Phi, Plo, W2hi, W2lo, b2, T2);
    agg_sliced<<<4 * NGRP, 256, 0, stream>>>((const unsigned*)T2, deg, csr,
                                             Phi, Plo, P, 1);
    pool_final<<<N_GRAPHS, 128, 0, stream>>>(P, gstart, Wout, bout, out);
}

// Round 19
// 194.605 us; speedup vs baseline: 1.9976x; 1.9976x over previous
//
#include <hip/hip_runtime.h>
#include <hip/hip_bf16.h>
#include <math.h>

#define N_NODES 50000
#define N_EDGES 600000
#define N_GRAPHS 512
#define DIM 128
#define OUTD 64
#define EPSV 1e-6f
#define BSTRIDE 64     // bucket slots per node; mean deg 12, P(deg>64) ~ 0
#define EBLK4 586      // ceil(150000 quads / 256)
#define PREP_BLK 64    // 16384 threads = DIM*DIM

typedef __attribute__((ext_vector_type(8))) short bf16x8;
typedef __attribute__((ext_vector_type(4))) float f32x4;

__device__ __forceinline__ float sgn(float v) {
    return (v > 0.f) ? 1.f : ((v < 0.f) ? -1.f : 0.f);
}

__device__ __forceinline__ float cube_signed(float v) {
    float m = fabsf(v) + EPSV;
    return sgn(v) * m * m * m;
}

__device__ __forceinline__ float cbrt_pos(float m) {
    return exp2f(log2f(m) * (1.0f / 3.0f));
}

__device__ __forceinline__ unsigned short f2bf(float f) {
    unsigned u = __float_as_uint(f);
    unsigned r = (u + 0x7fff + ((u >> 16) & 1)) >> 16;   // RNE
    return (unsigned short)r;
}

__device__ __forceinline__ float bf2f(unsigned short h) {
    return __uint_as_float(((unsigned)h) << 16);
}

// Dual-node wide gather: 2 nodes per wave, loads for BOTH nodes issued
// back-to-back -> 8 independent dwordx4 in flight (vs 4). Slots beyond a
// node's cnt resolve to index 0 (dummy zero row, L2-hot) -> exact zeros,
// no masking. lane&15 = feature octet, lane>>4 = edge slot within quad.
__device__ __forceinline__ void gather2(const unsigned* __restrict__ T32,
                                        const unsigned short* __restrict__ b0, int cnt0,
                                        const unsigned short* __restrict__ b1, int cnt1,
                                        int lane, float2 acc0[4], float2 acc1[4]) {
    #pragma unroll
    for (int j = 0; j < 4; j++) {
        acc0[j] = make_float2(0.f, 0.f);
        acc1[j] = make_float2(0.f, 0.f);
    }
    int my0 = (lane < cnt0) ? (int)b0[lane] : 0;
    int my1 = (lane < cnt1) ? (int)b1[lane] : 0;
    int sub = lane & 15, grp = lane >> 4;
    int cm = cnt0 > cnt1 ? cnt0 : cnt1;
    int cm16 = (cm + 15) & ~15;
    for (int i = 0; i < cm16; i += 16) {
        uint4 u0[4], u1[4];
        #pragma unroll
        for (int c = 0; c < 4; c++) {
            int s = __shfl(my0, i + c * 4 + grp, 64);
            u0[c] = *(const uint4*)(T32 + (size_t)s * 64 + sub * 4);
        }
        #pragma unroll
        for (int c = 0; c < 4; c++) {
            int s = __shfl(my1, i + c * 4 + grp, 64);
            u1[c] = *(const uint4*)(T32 + (size_t)s * 64 + sub * 4);
        }
        #pragma unroll
        for (int c = 0; c < 4; c++) {
            acc0[0].x += __uint_as_float(u0[c].x << 16);
            acc0[0].y += __uint_as_float(u0[c].x & 0xffff0000u);
            acc0[1].x += __uint_as_float(u0[c].y << 16);
            acc0[1].y += __uint_as_float(u0[c].y & 0xffff0000u);
            acc0[2].x += __uint_as_float(u0[c].z << 16);
            acc0[2].y += __uint_as_float(u0[c].z & 0xffff0000u);
            acc0[3].x += __uint_as_float(u0[c].w << 16);
            acc0[3].y += __uint_as_float(u0[c].w & 0xffff0000u);
            acc1[0].x += __uint_as_float(u1[c].x << 16);
            acc1[0].y += __uint_as_float(u1[c].x & 0xffff0000u);
            acc1[1].x += __uint_as_float(u1[c].y << 16);
            acc1[1].y += __uint_as_float(u1[c].y & 0xffff0000u);
            acc1[2].x += __uint_as_float(u1[c].z << 16);
            acc1[2].y += __uint_as_float(u1[c].z & 0xffff0000u);
            acc1[3].x += __uint_as_float(u1[c].w << 16);
            acc1[3].y += __uint_as_float(u1[c].w & 0xffff0000u);
        }
    }
    #pragma unroll
    for (int j = 0; j < 4; j++) {
        acc0[j].x += __shfl_xor(acc0[j].x, 16, 64);
        acc0[j].y += __shfl_xor(acc0[j].y, 16, 64);
        acc0[j].x += __shfl_xor(acc0[j].x, 32, 64);
        acc0[j].y += __shfl_xor(acc0[j].y, 32, 64);
        acc1[j].x += __shfl_xor(acc1[j].x, 16, 64);
        acc1[j].y += __shfl_xor(acc1[j].y, 16, 64);
        acc1[j].x += __shfl_xor(acc1[j].x, 32, 64);
        acc1[j].y += __shfl_xor(acc1[j].y, 32, 64);
    }
}

__device__ __forceinline__ float acc_pick_x(const float2 acc[4], int grp) {
    return grp == 0 ? acc[0].x : grp == 1 ? acc[1].x : grp == 2 ? acc[2].x : acc[3].x;
}
__device__ __forceinline__ float acc_pick_y(const float2 acc[4], int grp) {
    return grp == 0 ? acc[0].y : grp == 1 ? acc[1].y : grp == 2 ? acc[2].y : acc[3].y;
}

// ---- buildprep: 4-edge/thread bucket fill || W split + gstart + T zero -----
// deg must be zeroed (memsetAsync) before this kernel.

__global__ void buildprep(const int* __restrict__ src, const int* __restrict__ dst,
                          int* __restrict__ deg, unsigned short* __restrict__ csr,
                          const float* __restrict__ W1, const float* __restrict__ W2,
                          unsigned short* __restrict__ W1hi, unsigned short* __restrict__ W1lo,
                          unsigned short* __restrict__ W2hi, unsigned short* __restrict__ W2lo,
                          const int* __restrict__ batch, int* __restrict__ gstart,
                          unsigned* __restrict__ T1z, unsigned* __restrict__ T2z) {
    int b = blockIdx.x;
    if (b < EBLK4) {
        int e4 = b * 256 + threadIdx.x;
        if (e4 < N_EDGES / 4) {
            uint4 s4 = ((const uint4*)src)[e4];
            uint4 d4 = ((const uint4*)dst)[e4];
            int d0 = (int)d4.x, d1 = (int)d4.y, d2 = (int)d4.z, d3 = (int)d4.w;
            int sl0 = atomicAdd(&deg[d0], 1);
            int sl1 = atomicAdd(&deg[d1], 1);
            int sl2 = atomicAdd(&deg[d2], 1);
            int sl3 = atomicAdd(&deg[d3], 1);
            if (sl0 < BSTRIDE) csr[d0 * BSTRIDE + sl0] = (unsigned short)(s4.x + 1);
            if (sl1 < BSTRIDE) csr[d1 * BSTRIDE + sl1] = (unsigned short)(s4.y + 1);
            if (sl2 < BSTRIDE) csr[d2 * BSTRIDE + sl2] = (unsigned short)(s4.z + 1);
            if (sl3 < BSTRIDE) csr[d3 * BSTRIDE + sl3] = (unsigned short)(s4.w + 1);
        }
        return;
    }
    int i = (b - EBLK4) * 256 + threadIdx.x;
    {
        float w = W1[i];
        unsigned short h = f2bf(w);
        W1hi[i] = h;
        W1lo[i] = f2bf(w - bf2f(h));
        w = W2[i];
        h = f2bf(w);
        W2hi[i] = h;
        W2lo[i] = f2bf(w - bf2f(h));
    }
    if (i < 64) { T1z[i] = 0u; T2z[i] = 0u; }   // dummy zero row 0
    if (i <= N_GRAPHS) {
        int lo = 0, hi = N_NODES;
        while (lo < hi) {
            int mid = (lo + hi) >> 1;
            if (batch[mid] < i) lo = mid + 1; else hi = mid;
        }
        gstart[i] = lo;
    }
}

// ---- Linear+cube via split-bf16 MFMA: T[n+1] = cube(X @ W^T + B), bf16 -----
// R16-proven: wave owns 16-node tile, LDS-staged coalesced stores.

__global__ __launch_bounds__(256) void linear_cube_mfma(const float* __restrict__ X,
                                                        const unsigned short* __restrict__ Whi,
                                                        const unsigned short* __restrict__ Wlo,
                                                        const float* __restrict__ B,
                                                        unsigned short* __restrict__ T) {
    __shared__ unsigned short Tl[4][16][DIM];
    int wave = threadIdx.x >> 6;
    int lane = threadIdx.x & 63;
    int tile = blockIdx.x * 4 + wave;
    if (tile >= N_NODES / 16) return;
    int n0 = tile * 16;
    int r = lane & 15;    // A-row (node) on load side; B/D column (output)
    int g = lane >> 4;    // k-group

    bf16x8 xh[4], xl[4];
    const float* xrow = X + (size_t)(n0 + r) * DIM + g * 8;
    #pragma unroll
    for (int kb = 0; kb < 4; kb++) {
        float4 a = *(const float4*)(xrow + kb * 32);
        float4 b = *(const float4*)(xrow + kb * 32 + 4);
        float v[8] = {a.x, a.y, a.z, a.w, b.x, b.y, b.z, b.w};
        #pragma unroll
        for (int j = 0; j < 8; j++) {
            unsigned short h = f2bf(v[j]);
            float rem = v[j] - bf2f(h);
            xh[kb][j] = (short)h;
            xl[kb][j] = (short)f2bf(rem);
        }
    }

    #pragma unroll
    for (int ct = 0; ct < 8; ct++) {
        const unsigned short* whbase = Whi + (size_t)(ct * 16 + r) * DIM + g * 8;
        const unsigned short* wlbase = Wlo + (size_t)(ct * 16 + r) * DIM + g * 8;
        f32x4 acc = {0.f, 0.f, 0.f, 0.f};
        #pragma unroll
        for (int kb = 0; kb < 4; kb++) {
            bf16x8 wh = *(const bf16x8*)(whbase + kb * 32);
            bf16x8 wl = *(const bf16x8*)(wlbase + kb * 32);
            acc = __builtin_amdgcn_mfma_f32_16x16x32_bf16(xh[kb], wh, acc, 0, 0, 0);
            acc = __builtin_amdgcn_mfma_f32_16x16x32_bf16(xl[kb], wh, acc, 0, 0, 0);
            acc = __builtin_amdgcn_mfma_f32_16x16x32_bf16(xh[kb], wl, acc, 0, 0, 0);
        }
        float bias = B[ct * 16 + r];
        #pragma unroll
        for (int q = 0; q < 4; q++) {
            int node = g * 4 + q;   // D row = (lane>>4)*4 + reg  [m89]
            float h = acc[q] + bias;
            Tl[wave][node][ct * 16 + r] = f2bf(cube_signed(h));
        }
    }

    uint4* dstg = (uint4*)(T + (size_t)(n0 + 1) * DIM);
    const uint4* srcl = (const uint4*)&Tl[wave][0][0];
    #pragma unroll
    for (int i = 0; i < 4; i++) {
        dstg[i * 64 + lane] = srcl[i * 64 + lane];
    }
}

// ---- Fused: aggregate(layer1)+ReLU -> split -> LDS bf16 planes -> MFMA -----
// 512 threads / 8 waves per 16-node tile; 2 nodes per wave via dual-issue
// gather2 (8 loads in flight).

__global__ __launch_bounds__(512) void agg_linear_cube(const unsigned* __restrict__ T32,
                                                       const int* __restrict__ deg,
                                                       const unsigned short* __restrict__ csr,
                                                       const unsigned short* __restrict__ Whi,
                                                       const unsigned short* __restrict__ Wlo,
                                                       const float* __restrict__ B,
                                                       unsigned short* __restrict__ Tout) {
    __shared__ __attribute__((aligned(16))) unsigned Phi[16][68];
    __shared__ __attribute__((aligned(16))) unsigned Plo[16][68];
    int wave = threadIdx.x >> 6;
    int lane = threadIdx.x & 63;
    int n0 = blockIdx.x * 16;
    int sub = lane & 15, grp = lane >> 4;

    // phase 1: dual-node gather + cbrt + relu + hi/lo split
    {
        int nd0 = n0 + wave * 2;
        int nd1 = nd0 + 1;
        int d0 = deg[nd0], d1 = deg[nd1];
        int c0 = d0 < BSTRIDE ? d0 : BSTRIDE;
        int c1 = d1 < BSTRIDE ? d1 : BSTRIDE;
        float2 acc0[4], acc1[4];
        gather2(T32, csr + (size_t)nd0 * BSTRIDE, c0,
                csr + (size_t)nd1 * BSTRIDE, c1, lane, acc0, acc1);
        #pragma unroll
        for (int q = 0; q < 2; q++) {
            const float2* acc = q ? acc1 : acc0;
            int d = q ? d1 : d0;
            int row = wave * 2 + q;
            float c = (float)(d > 1 ? d : 1);
            float m0 = acc_pick_x(acc, grp) / c;
            float m1 = acc_pick_y(acc, grp) / c;
            float r0 = fmaxf(sgn(m0) * cbrt_pos(fabsf(m0) + EPSV), 0.f);
            float r1 = fmaxf(sgn(m1) * cbrt_pos(fabsf(m1) + EPSV), 0.f);
            unsigned short h0 = f2bf(r0), h1 = f2bf(r1);
            unsigned short l0 = f2bf(r0 - bf2f(h0)), l1 = f2bf(r1 - bf2f(h1));
            Phi[row][sub * 4 + grp] = (unsigned)h0 | ((unsigned)h1 << 16);
            Plo[row][sub * 4 + grp] = (unsigned)l0 | ((unsigned)l1 << 16);
        }
    }
    __syncthreads();

    // phase 2: fragments straight from LDS planes
    int r = lane & 15;
    int g = lane >> 4;
    bf16x8 xh[4], xl[4];
    #pragma unroll
    for (int kb = 0; kb < 4; kb++) {
        xh[kb] = *(const bf16x8*)&Phi[r][kb * 16 + g * 4];
        xl[kb] = *(const bf16x8*)&Plo[r][kb * 16 + g * 4];
    }
    int ct = wave;
    const unsigned short* whbase = Whi + (size_t)(ct * 16 + r) * DIM + g * 8;
    const unsigned short* wlbase = Wlo + (size_t)(ct * 16 + r) * DIM + g * 8;
    f32x4 acc = {0.f, 0.f, 0.f, 0.f};
    #pragma unroll
    for (int kb = 0; kb < 4; kb++) {
        bf16x8 wh = *(const bf16x8*)(whbase + kb * 32);
        bf16x8 wl = *(const bf16x8*)(wlbase + kb * 32);
        acc = __builtin_amdgcn_mfma_f32_16x16x32_bf16(xh[kb], wh, acc, 0, 0, 0);
        acc = __builtin_amdgcn_mfma_f32_16x16x32_bf16(xl[kb], wh, acc, 0, 0, 0);
        acc = __builtin_amdgcn_mfma_f32_16x16x32_bf16(xh[kb], wl, acc, 0, 0, 0);
    }
    float bias = B[ct * 16 + r];
    #pragma unroll
    for (int q = 0; q < 4; q++) {
        int node = g * 4 + q;
        float h = acc[q] + bias;
        Tout[(size_t)(n0 + node + 1) * DIM + ct * 16 + r] = f2bf(cube_signed(h));
    }
}

// ---- Conv aggregate (layer 2): 2 nodes per wave, dual-issue gather ---------

__global__ __launch_bounds__(256) void aggregate(const unsigned* __restrict__ T32,
                                                 const int* __restrict__ deg,
                                                 const unsigned short* __restrict__ csr,
                                                 float* __restrict__ P) {
    int base = blockIdx.x * 8 + (threadIdx.x >> 6) * 2;
    if (base >= N_NODES) return;
    int lane = threadIdx.x & 63;
    int sub = lane & 15, grp = lane >> 4;
    int nd0 = base, nd1 = base + 1;
    int d0 = deg[nd0], d1 = deg[nd1];
    int c0 = d0 < BSTRIDE ? d0 : BSTRIDE;
    int c1 = d1 < BSTRIDE ? d1 : BSTRIDE;
    float2 acc0[4], acc1[4];
    gather2(T32, csr + (size_t)nd0 * BSTRIDE, c0,
            csr + (size_t)nd1 * BSTRIDE, c1, lane, acc0, acc1);
    #pragma unroll
    for (int q = 0; q < 2; q++) {
        const float2* acc = q ? acc1 : acc0;
        int d = q ? d1 : d0;
        int nd = q ? nd1 : nd0;
        float c = (float)(d > 1 ? d : 1);
        float m0 = acc_pick_x(acc, grp) / c;
        float m1 = acc_pick_y(acc, grp) / c;
        float r0 = sgn(m0) * cbrt_pos(fabsf(m0) + EPSV);
        float r1 = sgn(m1) * cbrt_pos(fabsf(m1) + EPSV);
        *(float2*)(P + (size_t)nd * DIM + sub * 8 + grp * 2) = make_float2(r0, r1);
    }
}

// ---- Fused graph pool + final linear ---------------------------------------

__global__ __launch_bounds__(128) void pool_final(const float* __restrict__ P,
                                                  const int* __restrict__ gstart,
                                                  const float* __restrict__ Wout,
                                                  const float* __restrict__ bout,
                                                  float* __restrict__ out) {
    __shared__ float R[DIM];
    __shared__ float partial[128];
    int g = blockIdx.x, f = threadIdx.x;
    int s = gstart[g], e = gstart[g + 1];
    float acc = 0.f;
    for (int i = s; i < e; i++) {
        float v = P[(size_t)i * DIM + f];
        float m = fabsf(v) + EPSV;
        acc += sgn(v) * m * m;
    }
    int cnt = e - s;
    float c = (float)(cnt > 1 ? cnt : 1);
    float mean = acc / c;
    R[f] = sgn(mean) * sqrtf(fabsf(mean) + EPSV);
    __syncthreads();

    int o = f & 63;
    int half = f >> 6;
    const float4* W4 = (const float4*)Wout + o * 32 + half * 16;
    const float4* R4 = (const float4*)R + half * 16;
    float a = 0.f;
    #pragma unroll
    for (int k = 0; k < 16; k++) {
        float4 w = W4[k];
        float4 r = R4[k];
        a += r.x * w.x + r.y * w.y + r.z * w.z + r.w * w.w;
    }
    partial[f] = a;
    __syncthreads();
    if (f < OUTD) out[(size_t)g * OUTD + f] = bout[f] + partial[f] + partial[f + 64];
}

// ---- launch ----------------------------------------------------------------

extern "C" void kernel_launch(void* const* d_in, const int* in_sizes, int n_in,
                              void* d_out, int out_size, void* d_ws, size_t ws_size,
                              hipStream_t stream) {
    const float* x    = (const float*)d_in[0];
    const float* W1   = (const float*)d_in[1];
    const float* b1   = (const float*)d_in[2];
    const float* W2   = (const float*)d_in[3];
    const float* b2   = (const float*)d_in[4];
    const float* Wout = (const float*)d_in[5];
    const float* bout = (const float*)d_in[6];
    const int* edge   = (const int*)d_in[7];
    const int* batch  = (const int*)d_in[8];
    const int* srcp = edge;
    const int* dstp = edge + N_EDGES;
    float* out = (float*)d_out;

    char* ws = (char*)d_ws;
    size_t off = 0;
    auto alloc = [&](size_t bytes) -> char* {
        char* p = ws + off;
        off += (bytes + 255) / 256 * 256;
        return p;
    };
    unsigned short* T1 = (unsigned short*)alloc((size_t)(N_NODES + 1) * DIM * 2);
    unsigned short* T2 = (unsigned short*)alloc((size_t)(N_NODES + 1) * DIM * 2);
    float* P        = (float*)alloc((size_t)N_NODES * DIM * 4);
    int*   deg      = (int*)alloc((size_t)N_NODES * 4);
    unsigned short* csr = (unsigned short*)alloc((size_t)N_NODES * BSTRIDE * 2);
    int*   gstart   = (int*)alloc((size_t)(N_GRAPHS + 1) * 4);
    unsigned short* W1hi = (unsigned short*)alloc((size_t)DIM * DIM * 2);
    unsigned short* W1lo = (unsigned short*)alloc((size_t)DIM * DIM * 2);
    unsigned short* W2hi = (unsigned short*)alloc((size_t)DIM * DIM * 2);
    unsigned short* W2lo = (unsigned short*)alloc((size_t)DIM * DIM * 2);

    hipMemsetAsync(deg, 0, (size_t)N_NODES * 4, stream);
    buildprep<<<EBLK4 + PREP_BLK, 256, 0, stream>>>(srcp, dstp, deg, csr,
                                                    W1, W2, W1hi, W1lo, W2hi, W2lo,
                                                    batch, gstart,
                                                    (unsigned*)T1, (unsigned*)T2);

    const int TILES = N_NODES / 16;           // 3125
    const int LBLK = (TILES + 3) / 4;         // 782 blocks x 4 waves
    const int ABLK = (N_NODES + 7) / 8;       // 6250 blocks x 4 waves x 2 nodes
    linear_cube_mfma<<<LBLK, 256, 0, stream>>>(x, W1hi, W1lo, b1, T1);
    agg_linear_cube<<<TILES, 512, 0, stream>>>((const unsigned*)T1, deg, csr,
                                               W2hi, W2lo, b2, T2);
    aggregate<<<ABLK, 256, 0, stream>>>((const unsigned*)T2, deg, csr, P);
    pool_final<<<N_GRAPHS, 128, 0, stream>>>(P, gstart, Wout, bout, out);
}

// Round 20
// 182.123 us; speedup vs baseline: 2.1345x; 1.0685x over previous
//
#include <hip/hip_runtime.h>
#include <hip/hip_bf16.h>
#include <math.h>

#define N_NODES 50000
#define N_EDGES 600000
#define N_GRAPHS 512
#define DIM 128
#define OUTD 64
#define EPSV 1e-6f
#define BSTRIDE 64     // bucket slots per node; mean deg 12, P(deg>64) ~ 0
#define EBLK4 586      // ceil(150000 quads / 256)
#define PREP_BLK 64    // 16384 threads = DIM*DIM

typedef __attribute__((ext_vector_type(8))) short bf16x8;
typedef __attribute__((ext_vector_type(4))) float f32x4;

__device__ __forceinline__ float sgn(float v) {
    return (v > 0.f) ? 1.f : ((v < 0.f) ? -1.f : 0.f);
}

__device__ __forceinline__ float cube_signed(float v) {
    float m = fabsf(v) + EPSV;
    return sgn(v) * m * m * m;
}

__device__ __forceinline__ float cbrt_pos(float m) {
    return exp2f(log2f(m) * (1.0f / 3.0f));
}

__device__ __forceinline__ unsigned short f2bf(float f) {
    unsigned u = __float_as_uint(f);
    unsigned r = (u + 0x7fff + ((u >> 16) & 1)) >> 16;   // RNE
    return (unsigned short)r;
}

__device__ __forceinline__ float bf2f(unsigned short h) {
    return __uint_as_float(((unsigned)h) << 16);
}

// Wide gather (R10-proven): lane&15 = feature octet, lane>>4 = edge slot.
// One uint4 load = 4 edges x 256B. Out-of-range slots masked ONCE at bucket
// load (idx 0 = dummy zero row of T) -> no csr memset needed.
__device__ __forceinline__ void gather_acc8(const unsigned* __restrict__ T32,
                                            const unsigned short* __restrict__ bucket,
                                            int cnt, int lane, float2 acc[4]) {
    #pragma unroll
    for (int j = 0; j < 4; j++) acc[j] = make_float2(0.f, 0.f);
    if (cnt <= 0) return;
    int myidx = (lane < cnt) ? (int)bucket[lane] : 0;   // coalesced 128B
    int sub = lane & 15, grp = lane >> 4;
    int cnt16 = (cnt + 15) & ~15;
    for (int i = 0; i < cnt16; i += 16) {
        uint4 u[4];
        #pragma unroll
        for (int c = 0; c < 4; c++) {
            int s = __shfl(myidx, i + c * 4 + grp, 64);
            u[c] = *(const uint4*)(T32 + (size_t)s * 64 + sub * 4);
        }
        #pragma unroll
        for (int c = 0; c < 4; c++) {
            acc[0].x += __uint_as_float(u[c].x << 16);
            acc[0].y += __uint_as_float(u[c].x & 0xffff0000u);
            acc[1].x += __uint_as_float(u[c].y << 16);
            acc[1].y += __uint_as_float(u[c].y & 0xffff0000u);
            acc[2].x += __uint_as_float(u[c].z << 16);
            acc[2].y += __uint_as_float(u[c].z & 0xffff0000u);
            acc[3].x += __uint_as_float(u[c].w << 16);
            acc[3].y += __uint_as_float(u[c].w & 0xffff0000u);
        }
    }
    #pragma unroll
    for (int j = 0; j < 4; j++) {
        acc[j].x += __shfl_xor(acc[j].x, 16, 64);
        acc[j].y += __shfl_xor(acc[j].y, 16, 64);
        acc[j].x += __shfl_xor(acc[j].x, 32, 64);
        acc[j].y += __shfl_xor(acc[j].y, 32, 64);
    }
}

__device__ __forceinline__ float acc_pick_x(const float2 acc[4], int grp) {
    return grp == 0 ? acc[0].x : grp == 1 ? acc[1].x : grp == 2 ? acc[2].x : acc[3].x;
}
__device__ __forceinline__ float acc_pick_y(const float2 acc[4], int grp) {
    return grp == 0 ? acc[0].y : grp == 1 ? acc[1].y : grp == 2 ? acc[2].y : acc[3].y;
}

// ---- buildprep: 4-edge/thread bucket fill || W split + gstart + T zero -----
// deg must be zeroed (memsetAsync) before this kernel.

__global__ void buildprep(const int* __restrict__ src, const int* __restrict__ dst,
                          int* __restrict__ deg, unsigned short* __restrict__ csr,
                          const float* __restrict__ W1, const float* __restrict__ W2,
                          unsigned short* __restrict__ W1hi, unsigned short* __restrict__ W1lo,
                          unsigned short* __restrict__ W2hi, unsigned short* __restrict__ W2lo,
                          const int* __restrict__ batch, int* __restrict__ gstart,
                          unsigned* __restrict__ T1z, unsigned* __restrict__ T2z) {
    int b = blockIdx.x;
    if (b < EBLK4) {
        int e4 = b * 256 + threadIdx.x;
        if (e4 < N_EDGES / 4) {
            uint4 s4 = ((const uint4*)src)[e4];
            uint4 d4 = ((const uint4*)dst)[e4];
            int d0 = (int)d4.x, d1 = (int)d4.y, d2 = (int)d4.z, d3 = (int)d4.w;
            int sl0 = atomicAdd(&deg[d0], 1);
            int sl1 = atomicAdd(&deg[d1], 1);
            int sl2 = atomicAdd(&deg[d2], 1);
            int sl3 = atomicAdd(&deg[d3], 1);
            if (sl0 < BSTRIDE) csr[d0 * BSTRIDE + sl0] = (unsigned short)(s4.x + 1);
            if (sl1 < BSTRIDE) csr[d1 * BSTRIDE + sl1] = (unsigned short)(s4.y + 1);
            if (sl2 < BSTRIDE) csr[d2 * BSTRIDE + sl2] = (unsigned short)(s4.z + 1);
            if (sl3 < BSTRIDE) csr[d3 * BSTRIDE + sl3] = (unsigned short)(s4.w + 1);
        }
        return;
    }
    int i = (b - EBLK4) * 256 + threadIdx.x;
    {
        float w = W1[i];
        unsigned short h = f2bf(w);
        W1hi[i] = h;
        W1lo[i] = f2bf(w - bf2f(h));
        w = W2[i];
        h = f2bf(w);
        W2hi[i] = h;
        W2lo[i] = f2bf(w - bf2f(h));
    }
    if (i < 64) { T1z[i] = 0u; T2z[i] = 0u; }   // dummy zero row 0
    if (i <= N_GRAPHS) {
        int lo = 0, hi = N_NODES;
        while (lo < hi) {
            int mid = (lo + hi) >> 1;
            if (batch[mid] < i) lo = mid + 1; else hi = mid;
        }
        gstart[i] = lo;
    }
}

// ---- Linear+cube via split-bf16 MFMA: T[n+1] = cube(X @ W^T + B), bf16 -----
// R16-proven: wave owns 16-node tile, LDS-staged coalesced stores.

__global__ __launch_bounds__(256) void linear_cube_mfma(const float* __restrict__ X,
                                                        const unsigned short* __restrict__ Whi,
                                                        const unsigned short* __restrict__ Wlo,
                                                        const float* __restrict__ B,
                                                        unsigned short* __restrict__ T) {
    __shared__ unsigned short Tl[4][16][DIM];
    int wave = threadIdx.x >> 6;
    int lane = threadIdx.x & 63;
    int tile = blockIdx.x * 4 + wave;
    if (tile >= N_NODES / 16) return;
    int n0 = tile * 16;
    int r = lane & 15;    // A-row (node) on load side; B/D column (output)
    int g = lane >> 4;    // k-group

    bf16x8 xh[4], xl[4];
    const float* xrow = X + (size_t)(n0 + r) * DIM + g * 8;
    #pragma unroll
    for (int kb = 0; kb < 4; kb++) {
        float4 a = *(const float4*)(xrow + kb * 32);
        float4 b = *(const float4*)(xrow + kb * 32 + 4);
        float v[8] = {a.x, a.y, a.z, a.w, b.x, b.y, b.z, b.w};
        #pragma unroll
        for (int j = 0; j < 8; j++) {
            unsigned short h = f2bf(v[j]);
            float rem = v[j] - bf2f(h);
            xh[kb][j] = (short)h;
            xl[kb][j] = (short)f2bf(rem);
        }
    }

    #pragma unroll
    for (int ct = 0; ct < 8; ct++) {
        const unsigned short* whbase = Whi + (size_t)(ct * 16 + r) * DIM + g * 8;
        const unsigned short* wlbase = Wlo + (size_t)(ct * 16 + r) * DIM + g * 8;
        f32x4 acc = {0.f, 0.f, 0.f, 0.f};
        #pragma unroll
        for (int kb = 0; kb < 4; kb++) {
            bf16x8 wh = *(const bf16x8*)(whbase + kb * 32);
            bf16x8 wl = *(const bf16x8*)(wlbase + kb * 32);
            acc = __builtin_amdgcn_mfma_f32_16x16x32_bf16(xh[kb], wh, acc, 0, 0, 0);
            acc = __builtin_amdgcn_mfma_f32_16x16x32_bf16(xl[kb], wh, acc, 0, 0, 0);
            acc = __builtin_amdgcn_mfma_f32_16x16x32_bf16(xh[kb], wl, acc, 0, 0, 0);
        }
        float bias = B[ct * 16 + r];
        #pragma unroll
        for (int q = 0; q < 4; q++) {
            int node = g * 4 + q;   // D row = (lane>>4)*4 + reg  [m89]
            float h = acc[q] + bias;
            Tl[wave][node][ct * 16 + r] = f2bf(cube_signed(h));
        }
    }

    uint4* dstg = (uint4*)(T + (size_t)(n0 + 1) * DIM);
    const uint4* srcl = (const uint4*)&Tl[wave][0][0];
    #pragma unroll
    for (int i = 0; i < 4; i++) {
        dstg[i * 64 + lane] = srcl[i * 64 + lane];
    }
}

// ---- Fused: aggregate(layer1)+ReLU -> split -> LDS bf16 planes -> MFMA -----
// R10-proven: 512 threads / 8 waves per 16-node tile; 2 nodes per wave.

__global__ __launch_bounds__(512) void agg_linear_cube(const unsigned* __restrict__ T32,
                                                       const int* __restrict__ deg,
                                                       const unsigned short* __restrict__ csr,
                                                       const unsigned short* __restrict__ Whi,
                                                       const unsigned short* __restrict__ Wlo,
                                                       const float* __restrict__ B,
                                                       unsigned short* __restrict__ Tout) {
    __shared__ __attribute__((aligned(16))) unsigned Phi[16][68];
    __shared__ __attribute__((aligned(16))) unsigned Plo[16][68];
    int wave = threadIdx.x >> 6;
    int lane = threadIdx.x & 63;
    int n0 = blockIdx.x * 16;
    int sub = lane & 15, grp = lane >> 4;

    // phase 1: aggregate + cbrt + relu + hi/lo split (2 nodes per wave)
    #pragma unroll
    for (int q = 0; q < 2; q++) {
        int row = wave * 2 + q;
        int nd = n0 + row;
        int d = deg[nd];
        int cnt = d < BSTRIDE ? d : BSTRIDE;
        float2 acc[4];
        gather_acc8(T32, csr + (size_t)nd * BSTRIDE, cnt, lane, acc);
        float c = (float)(d > 1 ? d : 1);
        float m0 = acc_pick_x(acc, grp) / c;
        float m1 = acc_pick_y(acc, grp) / c;
        float r0 = fmaxf(sgn(m0) * cbrt_pos(fabsf(m0) + EPSV), 0.f);
        float r1 = fmaxf(sgn(m1) * cbrt_pos(fabsf(m1) + EPSV), 0.f);
        unsigned short h0 = f2bf(r0), h1 = f2bf(r1);
        unsigned short l0 = f2bf(r0 - bf2f(h0)), l1 = f2bf(r1 - bf2f(h1));
        Phi[row][sub * 4 + grp] = (unsigned)h0 | ((unsigned)h1 << 16);
        Plo[row][sub * 4 + grp] = (unsigned)l0 | ((unsigned)l1 << 16);
    }
    __syncthreads();

    // phase 2: fragments straight from LDS planes
    int r = lane & 15;
    int g = lane >> 4;
    bf16x8 xh[4], xl[4];
    #pragma unroll
    for (int kb = 0; kb < 4; kb++) {
        xh[kb] = *(const bf16x8*)&Phi[r][kb * 16 + g * 4];
        xl[kb] = *(const bf16x8*)&Plo[r][kb * 16 + g * 4];
    }
    int ct = wave;
    const unsigned short* whbase = Whi + (size_t)(ct * 16 + r) * DIM + g * 8;
    const unsigned short* wlbase = Wlo + (size_t)(ct * 16 + r) * DIM + g * 8;
    f32x4 acc = {0.f, 0.f, 0.f, 0.f};
    #pragma unroll
    for (int kb = 0; kb < 4; kb++) {
        bf16x8 wh = *(const bf16x8*)(whbase + kb * 32);
        bf16x8 wl = *(const bf16x8*)(wlbase + kb * 32);
        acc = __builtin_amdgcn_mfma_f32_16x16x32_bf16(xh[kb], wh, acc, 0, 0, 0);
        acc = __builtin_amdgcn_mfma_f32_16x16x32_bf16(xl[kb], wh, acc, 0, 0, 0);
        acc = __builtin_amdgcn_mfma_f32_16x16x32_bf16(xh[kb], wl, acc, 0, 0, 0);
    }
    float bias = B[ct * 16 + r];
    #pragma unroll
    for (int q = 0; q < 4; q++) {
        int node = g * 4 + q;
        float h = acc[q] + bias;
        Tout[(size_t)(n0 + node + 1) * DIM + ct * 16 + r] = f2bf(cube_signed(h));
    }
}

// ---- Conv aggregate (layer 2): mean of bf16 cubes -> signed cbrt -> P fp32 -

__global__ __launch_bounds__(256) void aggregate(const unsigned* __restrict__ T32,
                                                 const int* __restrict__ deg,
                                                 const unsigned short* __restrict__ csr,
                                                 float* __restrict__ P) {
    int nd = blockIdx.x * 4 + (threadIdx.x >> 6);
    if (nd >= N_NODES) return;
    int lane = threadIdx.x & 63;
    int sub = lane & 15, grp = lane >> 4;
    int d = deg[nd];
    int cnt = d < BSTRIDE ? d : BSTRIDE;
    float2 acc[4];
    gather_acc8(T32, csr + (size_t)nd * BSTRIDE, cnt, lane, acc);
    float c = (float)(d > 1 ? d : 1);
    float m0 = acc_pick_x(acc, grp) / c;
    float m1 = acc_pick_y(acc, grp) / c;
    float r0 = sgn(m0) * cbrt_pos(fabsf(m0) + EPSV);
    float r1 = sgn(m1) * cbrt_pos(fabsf(m1) + EPSV);
    *(float2*)(P + (size_t)nd * DIM + sub * 8 + grp * 2) = make_float2(r0, r1);
}

// ---- Fused graph pool + final linear ---------------------------------------

__global__ __launch_bounds__(128) void pool_final(const float* __restrict__ P,
                                                  const int* __restrict__ gstart,
                                                  const float* __restrict__ Wout,
                                                  const float* __restrict__ bout,
                                                  float* __restrict__ out) {
    __shared__ float R[DIM];
    __shared__ float partial[128];
    int g = blockIdx.x, f = threadIdx.x;
    int s = gstart[g], e = gstart[g + 1];
    float acc = 0.f;
    for (int i = s; i < e; i++) {
        float v = P[(size_t)i * DIM + f];
        float m = fabsf(v) + EPSV;
        acc += sgn(v) * m * m;
    }
    int cnt = e - s;
    float c = (float)(cnt > 1 ? cnt : 1);
    float mean = acc / c;
    R[f] = sgn(mean) * sqrtf(fabsf(mean) + EPSV);
    __syncthreads();

    int o = f & 63;
    int half = f >> 6;
    const float4* W4 = (const float4*)Wout + o * 32 + half * 16;
    const float4* R4 = (const float4*)R + half * 16;
    float a = 0.f;
    #pragma unroll
    for (int k = 0; k < 16; k++) {
        float4 w = W4[k];
        float4 r = R4[k];
        a += r.x * w.x + r.y * w.y + r.z * w.z + r.w * w.w;
    }
    partial[f] = a;
    __syncthreads();
    if (f < OUTD) out[(size_t)g * OUTD + f] = bout[f] + partial[f] + partial[f + 64];
}

// ---- launch ----------------------------------------------------------------

extern "C" void kernel_launch(void* const* d_in, const int* in_sizes, int n_in,
                              void* d_out, int out_size, void* d_ws, size_t ws_size,
                              hipStream_t stream) {
    const float* x    = (const float*)d_in[0];
    const float* W1   = (const float*)d_in[1];
    const float* b1   = (const float*)d_in[2];
    const float* W2   = (const float*)d_in[3];
    const float* b2   = (const float*)d_in[4];
    const float* Wout = (const float*)d_in[5];
    const float* bout = (const float*)d_in[6];
    const int* edge   = (const int*)d_in[7];
    const int* batch  = (const int*)d_in[8];
    const int* srcp = edge;
    const int* dstp = edge + N_EDGES;
    float* out = (float*)d_out;

    char* ws = (char*)d_ws;
    size_t off = 0;
    auto alloc = [&](size_t bytes) -> char* {
        char* p = ws + off;
        off += (bytes + 255) / 256 * 256;
        return p;
    };
    unsigned short* T1 = (unsigned short*)alloc((size_t)(N_NODES + 1) * DIM * 2);
    unsigned short* T2 = (unsigned short*)alloc((size_t)(N_NODES + 1) * DIM * 2);
    float* P        = (float*)alloc((size_t)N_NODES * DIM * 4);
    int*   deg      = (int*)alloc((size_t)N_NODES * 4);
    unsigned short* csr = (unsigned short*)alloc((size_t)N_NODES * BSTRIDE * 2);
    int*   gstart   = (int*)alloc((size_t)(N_GRAPHS + 1) * 4);
    unsigned short* W1hi = (unsigned short*)alloc((size_t)DIM * DIM * 2);
    unsigned short* W1lo = (unsigned short*)alloc((size_t)DIM * DIM * 2);
    unsigned short* W2hi = (unsigned short*)alloc((size_t)DIM * DIM * 2);
    unsigned short* W2lo = (unsigned short*)alloc((size_t)DIM * DIM * 2);

    hipMemsetAsync(deg, 0, (size_t)N_NODES * 4, stream);
    buildprep<<<EBLK4 + PREP_BLK, 256, 0, stream>>>(srcp, dstp, deg, csr,
                                                    W1, W2, W1hi, W1lo, W2hi, W2lo,
                                                    batch, gstart,
                                                    (unsigned*)T1, (unsigned*)T2);

    const int TILES = N_NODES / 16;           // 3125
    const int LBLK = (TILES + 3) / 4;         // 782 blocks x 4 waves
    const int ABLK = (N_NODES + 3) / 4;       // 12500 blocks x 4 waves
    linear_cube_mfma<<<LBLK, 256, 0, stream>>>(x, W1hi, W1lo, b1, T1);
    agg_linear_cube<<<TILES, 512, 0, stream>>>((const unsigned*)T1, deg, csr,
                                               W2hi, W2lo, b2, T2);
    aggregate<<<ABLK, 256, 0, stream>>>((const unsigned*)T2, deg, csr, P);
    pool_final<<<N_GRAPHS, 128, 0, stream>>>(P, gstart, Wout, bout, out);
}